// Round 3
// baseline (425.101 us; speedup 1.0000x reference)
//
#include <hip/hip_runtime.h>
#include <hip/hip_bf16.h>
#include <math.h>

#define NN 100000
#define NE 1600000
#define NP 500000
#define HD 128
#define NPB 128                    // nodes per bucket (pow2)
#define NB 782                     // ceil(NN/NPB)
#define CAP 2560                   // bucket capacity (mean 2048, +11 sigma)

typedef __attribute__((ext_vector_type(8))) short short8;   // 8 bf16 = 4 VGPRs
typedef __attribute__((ext_vector_type(4))) float f32x4;

// ---- bf16 helpers ----
__device__ __forceinline__ float bf_lo(unsigned int u) { return __uint_as_float(u << 16); }
__device__ __forceinline__ float bf_hi(unsigned int u) { return __uint_as_float(u & 0xffff0000u); }
__device__ __forceinline__ unsigned short bf16_rne(float f) {
  unsigned int u = __float_as_uint(f);
  u = (u + 0x7fffu + ((u >> 16) & 1u)) >> 16;
  return (unsigned short)u;
}
// accumulate 8 bf16 (one uint4) into ax[8]
__device__ __forceinline__ void acc_row8(float* ax, uint4 u) {
  ax[0] += bf_lo(u.x); ax[1] += bf_hi(u.x);
  ax[2] += bf_lo(u.y); ax[3] += bf_hi(u.y);
  ax[4] += bf_lo(u.z); ax[5] += bf_hi(u.z);
  ax[6] += bf_lo(u.w); ax[7] += bf_hi(u.w);
}

// ---------------- prep (fused): zero deg + W1 transpose/cast + u-vectors ----------------
// blocks 0..390: zero deg[100096]; blocks 391..454: wconv; block 455: uvec
__global__ __launch_bounds__(256) void k_prep(int* __restrict__ deg,
                                              const float* __restrict__ W1,
                                              unsigned short* __restrict__ Wt,
                                              const float* __restrict__ W2,
                                              const float* __restrict__ Wl,
                                              const float* __restrict__ b2,
                                              float* __restrict__ uv) {
  const int blk = blockIdx.x;
  const int t = threadIdx.x;
  if (blk < 391) {
    deg[blk * 256 + t] = 0;   // 391*256 = 100096 = NB*NPB exactly
  } else if (blk < 455) {
    int i = (blk - 391) * 256 + t;   // 16384
    int n = i >> 7, k = i & 127;
    Wt[i] = bf16_rne(W1[k * HD + n]);
  } else {
    // u-vectors: u1 = W2@Wl[:128], u2 = W2@Wl[128:], c1/c2 = b2.Wl
    __shared__ float sh[256];
    const int half = t >> 7;
    const int k = t & 127;
    const float* wl = Wl + half * 128;
    float s = 0.f;
    for (int c = 0; c < 128; ++c) s += W2[k * HD + c] * wl[c];
    uv[half * 128 + k] = s;

    sh[t] = b2[k] * Wl[half * 128 + k];
    __syncthreads();
    for (int o = 64; o > 0; o >>= 1) {
      if ((t & 127) < o) sh[t] += sh[t + o];
      __syncthreads();
    }
    if (t == 0) uv[256] = sh[0];
    if (t == 128) uv[257] = sh[128];
  }
}

// ---------------- deg: global atomic degree count ----------------
__global__ __launch_bounds__(256) void k_deg(const int* __restrict__ dst,
                                             int* __restrict__ deg, int ne) {
  const int e0 = blockIdx.x * 1024 + threadIdx.x;
#pragma unroll
  for (int k = 0; k < 4; ++k) {
    int e = e0 + k * 256;
    if (e < ne) atomicAdd(&deg[dst[e]], 1);
  }
}

// ---------------- rows: per-bucket scan -> rows/dinv/cursor + degree-sorted order ----------------
// 782 blocks x 128 threads; reads only 128 ints per block (replaces binB's 25.6MB re-reads)
__global__ __launch_bounds__(128) void k_rows(int* __restrict__ degcur,
                                              int2* __restrict__ rows,
                                              float* __restrict__ dinv,
                                              int* __restrict__ sortOrd) {
  __shared__ int sc[NPB];
  __shared__ int h64[64];
  __shared__ int s64[64];
  const int b = blockIdx.x;
  const int t = threadIdx.x;
  const int node = b * NPB + t;
  const bool valid = node < NN;

  const int v = valid ? degcur[node] : 0;   // pad region zeroed in k_prep
  sc[t] = v;
  if (t < 64) h64[t] = 0;
  __syncthreads();
#pragma unroll
  for (int o = 1; o < NPB; o <<= 1) {
    int add = (t >= o) ? sc[t - o] : 0;
    __syncthreads();
    sc[t] += add;
    __syncthreads();
  }
  if (valid) {
    int rp = b * CAP + sc[t] - v;   // exclusive prefix within bucket
    rows[node] = make_int2(rp, rp + v);
    degcur[node] = rp;              // becomes the placement cursor
    dinv[node] = rsqrtf((float)v + 1.0f);
  }

  // counting sort of the 128 local nodes by degree (invalid t -> deg 0)
  const int dcl = v > 63 ? 63 : v;
  atomicAdd(&h64[dcl], 1);
  __syncthreads();
  int hv = (t < 64) ? h64[t] : 0;
  if (t < 64) s64[t] = hv;
  __syncthreads();
#pragma unroll
  for (int o = 1; o < 64; o <<= 1) {
    int add = (t < 64 && t >= o) ? s64[t - o] : 0;
    __syncthreads();
    if (t < 64) s64[t] += add;
    __syncthreads();
  }
  if (t < 64) h64[t] = s64[t] - hv;  // exclusive base -> cursor
  __syncthreads();
  int p = atomicAdd(&h64[dcl], 1);
  sortOrd[b * NPB + p] = t;
}

// ---------------- place: direct CSR placement via per-node cursors ----------------
__global__ __launch_bounds__(256) void k_place(const int* __restrict__ src,
                                               const int* __restrict__ dst,
                                               int* __restrict__ degcur,
                                               int* __restrict__ col, int ne) {
  const int e0 = blockIdx.x * 1024 + threadIdx.x;
#pragma unroll
  for (int k = 0; k < 4; ++k) {
    int e = e0 + k * 256;
    if (e < ne) {
      int pos = atomicAdd(&degcur[dst[e]], 1);
      col[pos] = src[e];
    }
  }
}

// ---------------- MFMA GEMM -> row-major layout ----------------
// hs[row][f]: 128 bf16 = 256B per row, 256B-aligned (hs at ws offset 0)
__global__ __launch_bounds__(256) void k_gemm_mfma(const float* __restrict__ X,
                                                   const unsigned short* __restrict__ Wt,
                                                   const float* __restrict__ dinv,
                                                   unsigned short* __restrict__ hs,
                                                   int nrows) {
  const int wave = threadIdx.x >> 6;
  const int lane = threadIdx.x & 63;
  const int row0 = blockIdx.x * 64 + wave * 16;
  if (row0 >= nrows) return;
  const int lm = lane & 15;   // A-row / C-col
  const int lq = lane >> 4;   // quad

  int arow = row0 + lm;
  int arowc = arow < nrows ? arow : nrows - 1;  // clamp (stores are guarded)

  short8 afrag[4];
#pragma unroll
  for (int kc = 0; kc < 4; ++kc) {
    int k0 = kc * 32 + lq * 8;
    const float4* p = (const float4*)(X + (size_t)arowc * HD + k0);
    float4 f0 = p[0], f1 = p[1];
    short8 a;
    a[0] = (short)bf16_rne(f0.x); a[1] = (short)bf16_rne(f0.y);
    a[2] = (short)bf16_rne(f0.z); a[3] = (short)bf16_rne(f0.w);
    a[4] = (short)bf16_rne(f1.x); a[5] = (short)bf16_rne(f1.y);
    a[6] = (short)bf16_rne(f1.z); a[7] = (short)bf16_rne(f1.w);
    afrag[kc] = a;
  }

  float dv[4];
#pragma unroll
  for (int r = 0; r < 4; ++r) {
    int row = row0 + lq * 4 + r;
    dv[r] = dinv[row < nrows ? row : 0];
  }

#pragma unroll
  for (int nt = 0; nt < 8; ++nt) {
    f32x4 acc = {0.f, 0.f, 0.f, 0.f};
    const unsigned short* Wb = Wt + (size_t)(nt * 16 + lm) * HD + lq * 8;
#pragma unroll
    for (int kc = 0; kc < 4; ++kc) {
      short8 bfrag = *(const short8*)(Wb + kc * 32);
      acc = __builtin_amdgcn_mfma_f32_16x16x32_bf16(afrag[kc], bfrag, acc, 0, 0, 0);
    }
#pragma unroll
    for (int r = 0; r < 4; ++r) {
      int row = row0 + lq * 4 + r;
      if (row < nrows)
        hs[(size_t)row * HD + nt * 16 + lm] = bf16_rne(acc[r] * dv[r]);
    }
  }
}

// ---------------- row-gather: 16 lanes per node, full 256B row per edge ----------------
// Full-line gathers: 1 edge = 2 fully-used 128B lines; col read once.
// FETCH ~201MB == 8 XCD x 25.6MB hs: each XCD L2 fills each line once (structural floor).
// Stratified sorted-position map (p = gi*8 + s): waves keep ~uniform degree.
__global__ __launch_bounds__(256) void k_gatherR(const uint4* __restrict__ hsv,
                                                 const float* __restrict__ dinv,
                                                 const int2* __restrict__ rows,
                                                 const int* __restrict__ col,
                                                 const int* __restrict__ sortOrd,
                                                 const float* __restrict__ b1,
                                                 const float* __restrict__ uv,
                                                 float2* __restrict__ q) {
  const int s = blockIdx.x & 7;        // position slice
  const int g = blockIdx.x >> 3;       // bucket
  const int t = threadIdx.x;
  const int gi = t >> 4;               // group 0..15 (one node each)
  const int fl = t & 15;               // lane in group: feats [fl*8, fl*8+8)
  const int p = gi * 8 + s;            // stratified sorted position
  const int tloc = sortOrd[g * NPB + p];
  const int node = g * NPB + tloc;
  const bool valid = node < NN;

  int2 be = valid ? rows[node] : make_int2(0, 0);

  float ax[8] = {0.f, 0.f, 0.f, 0.f, 0.f, 0.f, 0.f, 0.f};
  if (valid) acc_row8(ax, hsv[(size_t)node * 16 + fl]);  // self term

  int e = be.x;
  const int eend = be.y;
  for (; e + 3 < eend; e += 4) {
    int c0 = col[e], c1 = col[e + 1], c2 = col[e + 2], c3 = col[e + 3];
    uint4 u0 = hsv[(size_t)c0 * 16 + fl];
    uint4 u1 = hsv[(size_t)c1 * 16 + fl];
    uint4 u2 = hsv[(size_t)c2 * 16 + fl];
    uint4 u3 = hsv[(size_t)c3 * 16 + fl];
    acc_row8(ax, u0); acc_row8(ax, u1); acc_row8(ax, u2); acc_row8(ax, u3);
  }
  for (; e < eend; ++e) acc_row8(ax, hsv[(size_t)col[e] * 16 + fl]);

  // epilogue: relu + projection over own 8 feats, reduce across the 16-lane group
  float di = valid ? dinv[node] : 0.f;
  float s1 = 0.f, s2 = 0.f;
#pragma unroll
  for (int j = 0; j < 8; ++j) {
    int f = fl * 8 + j;
    float h = fmaxf(di * ax[j] + b1[f], 0.f);
    s1 += h * uv[f];
    s2 += h * uv[128 + f];
  }
#pragma unroll
  for (int o = 1; o < 16; o <<= 1) {
    s1 += __shfl_xor(s1, o);
    s2 += __shfl_xor(s2, o);
  }
  if (fl == 0 && valid) q[node] = make_float2(di * s1, di * s2);
}

// ---------------- qagg: conv2+score collapsed (q table 800KB, L2-resident) ----------------
#define LOADQ(P0, P1, P2, P3, pos)                                     \
  {                                                                    \
    P0 = q[col[(pos)]]; P1 = q[col[(pos) + 1]];                        \
    P2 = q[col[(pos) + 2]]; P3 = q[col[(pos) + 3]];                    \
  }
__global__ __launch_bounds__(256) void k_qagg(const float2* __restrict__ q,
                                              const float* __restrict__ dinv,
                                              const int2* __restrict__ rows,
                                              const int* __restrict__ col,
                                              const float* __restrict__ uv,
                                              float2* __restrict__ sv, int n) {
  int i = blockIdx.x * 256 + threadIdx.x;
  if (i >= n) return;
  int2 be = rows[i];
  float2 a = q[i];
  float a1 = a.x, a2 = a.y;
  int e = be.x;
  const int eend = be.y;
  int n4 = (eend - e) >> 2;
  int ep = e;
  e += n4 << 2;
  if (n4) {
    float2 A0, A1, A2, A3, B0, B1, B2, B3;
    LOADQ(A0, A1, A2, A3, ep); ep += 4; n4--;
    while (n4 >= 2) {
      LOADQ(B0, B1, B2, B3, ep); ep += 4;
      a1 += (A0.x + A1.x) + (A2.x + A3.x);
      a2 += (A0.y + A1.y) + (A2.y + A3.y);
      LOADQ(A0, A1, A2, A3, ep); ep += 4;
      a1 += (B0.x + B1.x) + (B2.x + B3.x);
      a2 += (B0.y + B1.y) + (B2.y + B3.y);
      n4 -= 2;
    }
    if (n4) {
      LOADQ(B0, B1, B2, B3, ep);
      a1 += (A0.x + A1.x) + (A2.x + A3.x);
      a2 += (A0.y + A1.y) + (A2.y + A3.y);
      a1 += (B0.x + B1.x) + (B2.x + B3.x);
      a2 += (B0.y + B1.y) + (B2.y + B3.y);
    } else {
      a1 += (A0.x + A1.x) + (A2.x + A3.x);
      a2 += (A0.y + A1.y) + (A2.y + A3.y);
    }
  }
  for (; e < eend; ++e) {
    float2 qq = q[col[e]];
    a1 += qq.x; a2 += qq.y;
  }
  float di = dinv[i];
  sv[i] = make_float2(a1 * di + uv[256], a2 * di + uv[257]);
}

// ---------------- pair outputs ----------------
__global__ void k_pairs(const float2* __restrict__ s, const int* __restrict__ I,
                        const int* __restrict__ J, const float* __restrict__ blin,
                        float* __restrict__ out, int np) {
  int p = blockIdx.x * 256 + threadIdx.x;
  if (p < np) {
    float v = s[I[p]].x + s[J[p]].y + blin[0];
    out[p] = 1.f / (1.f + __expf(-v));
  }
}

extern "C" void kernel_launch(void* const* d_in, const int* in_sizes, int n_in,
                              void* d_out, int out_size, void* d_ws, size_t ws_size,
                              hipStream_t stream) {
  const float* x     = (const float*)d_in[0];
  const int*   eidx  = (const int*)d_in[1];
  const int*   Iidx  = (const int*)d_in[2];
  const int*   Jidx  = (const int*)d_in[3];
  const float* W1    = (const float*)d_in[4];
  const float* b1    = (const float*)d_in[5];
  const float* W2    = (const float*)d_in[6];
  const float* b2    = (const float*)d_in[7];
  const float* Wlin  = (const float*)d_in[8];
  const float* blin  = (const float*)d_in[9];
  const int* src = eidx;
  const int* dst = eidx + NE;

  // workspace layout: hs FIRST so rows are 256B-aligned (row = exactly two 128B lines)
  unsigned short* hs = (unsigned short*)d_ws;         // NN*HD bf16 = 25.6 MB
  float* dinv  = (float*)(hs + (size_t)NN * HD);      // 100000
  float* sv    = dinv + 100000;                       // 200000 (float2/node)
  float* qbuf  = sv + 200000;                         // 200000 (float2/node)
  float* uv    = qbuf + 200000;                       // 264
  unsigned short* wt1 = (unsigned short*)(uv + 264);  // 16384 bf16
  int2* rows   = (int2*)(wt1 + 16384);                // NN int2 (8B-aligned)
  int* col     = (int*)(rows + NN);                   // NB*CAP = 2001920
  int* degcur  = col + NB * CAP;                      // NB*NPB = 100096 (deg -> cursor)
  int* sortOrd = degcur + NB * NPB;                   // NB*NPB = 100096

  float* out = (float*)d_out;

  // ---- prep (zero deg + weight prep, fused) ----
  k_prep<<<456, 256, 0, stream>>>(degcur, W1, wt1, W2, Wlin, b2, uv);

  // ---- CSR build: deg count -> per-bucket scan -> direct placement ----
  k_deg<<<(NE + 1023) / 1024, 256, 0, stream>>>(dst, degcur, NE);
  k_rows<<<NB, 128, 0, stream>>>(degcur, rows, dinv, sortOrd);
  k_place<<<(NE + 1023) / 1024, 256, 0, stream>>>(src, dst, degcur, col, NE);

  // conv1 GEMM -> row-major hs
  k_gemm_mfma<<<(NN + 63) / 64, 256, 0, stream>>>(x, wt1, dinv, hs, NN);

  // conv1 aggregation + relu + score projection (16 lanes/node, full-line gathers)
  k_gatherR<<<NB * 8, 256, 0, stream>>>((const uint4*)hs, dinv, rows, col,
                                        sortOrd, b1, uv, (float2*)qbuf);

  // conv2 + score head collapsed (pipelined gathers)
  k_qagg<<<(NN + 255) / 256, 256, 0, stream>>>((const float2*)qbuf, dinv, rows, col, uv,
                                               (float2*)sv, NN);

  // pair outputs
  k_pairs<<<(NP + 255) / 256, 256, 0, stream>>>((const float2*)sv, Iidx, Jidx, blin, out, NP);
}

// Round 4
// 262.965 us; speedup vs baseline: 1.6166x; 1.6166x over previous
//
#include <hip/hip_runtime.h>
#include <hip/hip_bf16.h>
#include <math.h>

#define NN 100000
#define NE 1600000
#define NP 500000
#define HD 128
#define NPB 128                    // nodes per bucket (pow2)
#define NB 782                     // ceil(NN/NPB)
#define CAP 2560                   // bucket capacity (mean 2048, +11 sigma)
#define CHUNK 4096                 // edges per binning workgroup
#define NWG 391                    // ceil(NE/CHUNK)

typedef __attribute__((ext_vector_type(8))) short short8;   // 8 bf16 = 4 VGPRs
typedef __attribute__((ext_vector_type(4))) float f32x4;

// ---- bf16 helpers ----
__device__ __forceinline__ float bf_lo(unsigned int u) { return __uint_as_float(u << 16); }
__device__ __forceinline__ float bf_hi(unsigned int u) { return __uint_as_float(u & 0xffff0000u); }
__device__ __forceinline__ unsigned short bf16_rne(float f) {
  unsigned int u = __float_as_uint(f);
  u = (u + 0x7fffu + ((u >> 16) & 1u)) >> 16;
  return (unsigned short)u;
}
// accumulate 8 bf16 (one uint4) into ax[8]
__device__ __forceinline__ void acc_row8(float* ax, uint4 u) {
  ax[0] += bf_lo(u.x); ax[1] += bf_hi(u.x);
  ax[2] += bf_lo(u.y); ax[3] += bf_hi(u.y);
  ax[4] += bf_lo(u.z); ax[5] += bf_hi(u.z);
  ax[6] += bf_lo(u.w); ax[7] += bf_hi(u.w);
}

// ---------------- prep (fused): W1 transpose/cast + u-vectors + gcursor init ----------------
// blocks 0..63: wconv (16384); block 64: uvec; block 65: gcursor init
__global__ __launch_bounds__(256) void k_prep(const float* __restrict__ W1,
                                              unsigned short* __restrict__ Wt,
                                              const float* __restrict__ W2,
                                              const float* __restrict__ Wl,
                                              const float* __restrict__ b2,
                                              float* __restrict__ uv,
                                              int* __restrict__ gcursor) {
  const int blk = blockIdx.x;
  const int t = threadIdx.x;
  if (blk < 64) {
    int i = blk * 256 + t;           // 16384
    int n = i >> 7, k = i & 127;
    Wt[i] = bf16_rne(W1[k * HD + n]);
  } else if (blk == 64) {
    // u-vectors: u1 = W2@Wl[:128], u2 = W2@Wl[128:], c1/c2 = b2.Wl
    __shared__ float sh[256];
    const int half = t >> 7;
    const int k = t & 127;
    const float* wl = Wl + half * 128;
    float s = 0.f;
    for (int c = 0; c < 128; ++c) s += W2[k * HD + c] * wl[c];
    uv[half * 128 + k] = s;

    sh[t] = b2[k] * Wl[half * 128 + k];
    __syncthreads();
    for (int o = 64; o > 0; o >>= 1) {
      if ((t & 127) < o) sh[t] += sh[t + o];
      __syncthreads();
    }
    if (t == 0) uv[256] = sh[0];
    if (t == 128) uv[257] = sh[128];
  } else {
    for (int i = t; i < NB; i += 256) gcursor[i] = i * CAP;
  }
}

// ---- binA: bin edges into fixed-capacity bucket regions; 4B entry = src | (d&127)<<17 ----
// dst values staged in registers across the two passes (saves the 6.4MB re-read).
__global__ __launch_bounds__(256) void k_binA(const int* __restrict__ src,
                                              const int* __restrict__ dst,
                                              int* __restrict__ gcursor,
                                              unsigned* __restrict__ binned, int ne) {
  __shared__ int hist[NB];
  __shared__ int base[NB];
  const int t = threadIdx.x;
  const int e0 = blockIdx.x * CHUNK;

  for (int i = t; i < NB; i += 256) hist[i] = 0;
  __syncthreads();

  int dstv[CHUNK / 256];
#pragma unroll
  for (int k = 0; k < CHUNK / 256; ++k) {
    int e = e0 + k * 256 + t;
    dstv[k] = (e < ne) ? dst[e] : -1;
    if (dstv[k] >= 0) atomicAdd(&hist[dstv[k] >> 7], 1);
  }
  __syncthreads();

  for (int i = t; i < NB; i += 256) {
    int c = hist[i];
    base[i] = c ? atomicAdd(&gcursor[i], c) : 0;
    hist[i] = 0;
  }
  __syncthreads();

#pragma unroll
  for (int k = 0; k < CHUNK / 256; ++k) {
    int d = dstv[k];
    if (d >= 0) {
      int e = e0 + k * 256 + t;
      int b = d >> 7;
      int pos = base[b] + atomicAdd(&hist[b], 1);
      binned[pos] = (unsigned)src[e] | ((unsigned)(d & 127) << 17);
    }
  }
}

// ---- binB: per-node count -> rows + dinv + degree-sorted order, then CSR placement ----
// Bucket entries staged in LDS during the count pass; placement reads LDS (saves 12.8MB).
__global__ __launch_bounds__(256) void k_binB(const unsigned* __restrict__ binned,
                                              const int* __restrict__ gcursor,
                                              int2* __restrict__ rows,
                                              int* __restrict__ col,
                                              float* __restrict__ dinv,
                                              int* __restrict__ sortOrd) {
  __shared__ unsigned lbin[CAP];
  __shared__ int hcnt[NPB];
  __shared__ int sc[NPB];
  __shared__ int lcur[NPB];
  __shared__ int h64[64];
  __shared__ int s64[64];
  const int b = blockIdx.x;
  const int t = threadIdx.x;
  const int node0 = b * NPB;
  const int node1 = (node0 + NPB > NN) ? NN : node0 + NPB;
  const int nnode = node1 - node0;
  if (t < NPB) hcnt[t] = 0;
  if (t < 64) h64[t] = 0;
  __syncthreads();

  const int gbase = b * CAP;
  const int gend = gcursor[b];   // after binA: b*CAP + bucket count
  const int cnt = gend - gbase;
  for (int i = gbase + t; i < gend; i += 256) {
    unsigned en = binned[i];
    lbin[i - gbase] = en;
    atomicAdd(&hcnt[en >> 17], 1);
  }
  __syncthreads();

  int v = (t < NPB) ? hcnt[t] : 0;
  if (t < NPB) sc[t] = v;
  __syncthreads();
#pragma unroll
  for (int o = 1; o < NPB; o <<= 1) {
    int add = (t < NPB && t >= o) ? sc[t - o] : 0;
    __syncthreads();
    if (t < NPB) sc[t] += add;
    __syncthreads();
  }
  if (t < nnode) {
    int rp = gbase + sc[t] - v;   // exclusive prefix within bucket
    rows[node0 + t] = make_int2(rp, rp + v);
    lcur[t] = rp;
    dinv[node0 + t] = rsqrtf((float)v + 1.0f);
  }

  // ---- counting sort of the 128 local nodes by degree (invalid t -> deg 0) ----
  const int deg = (t < nnode) ? v : 0;
  const int dcl = deg > 63 ? 63 : deg;
  if (t < NPB) atomicAdd(&h64[dcl], 1);
  __syncthreads();
  int hv = (t < 64) ? h64[t] : 0;
  if (t < 64) s64[t] = hv;
  __syncthreads();
#pragma unroll
  for (int o = 1; o < 64; o <<= 1) {
    int add = (t < 64 && t >= o) ? s64[t - o] : 0;
    __syncthreads();
    if (t < 64) s64[t] += add;
    __syncthreads();
  }
  if (t < 64) h64[t] = s64[t] - hv;  // exclusive base -> cursor
  __syncthreads();
  if (t < NPB) {
    int p = atomicAdd(&h64[dcl], 1);
    sortOrd[b * NPB + p] = t;
  }
  __syncthreads();

  for (int i = t; i < cnt; i += 256) {
    unsigned en = lbin[i];
    int pos = atomicAdd(&lcur[en >> 17], 1);
    col[pos] = (int)(en & 0x1FFFF);
  }
}

// ---------------- MFMA GEMM -> row-major layout ----------------
// hs[row][f]: 128 bf16 = 256B per row, 256B-aligned (hs at ws offset 0)
__global__ __launch_bounds__(256) void k_gemm_mfma(const float* __restrict__ X,
                                                   const unsigned short* __restrict__ Wt,
                                                   const float* __restrict__ dinv,
                                                   unsigned short* __restrict__ hs,
                                                   int nrows) {
  const int wave = threadIdx.x >> 6;
  const int lane = threadIdx.x & 63;
  const int row0 = blockIdx.x * 64 + wave * 16;
  if (row0 >= nrows) return;
  const int lm = lane & 15;   // A-row / C-col
  const int lq = lane >> 4;   // quad

  int arow = row0 + lm;
  int arowc = arow < nrows ? arow : nrows - 1;  // clamp (stores are guarded)

  short8 afrag[4];
#pragma unroll
  for (int kc = 0; kc < 4; ++kc) {
    int k0 = kc * 32 + lq * 8;
    const float4* p = (const float4*)(X + (size_t)arowc * HD + k0);
    float4 f0 = p[0], f1 = p[1];
    short8 a;
    a[0] = (short)bf16_rne(f0.x); a[1] = (short)bf16_rne(f0.y);
    a[2] = (short)bf16_rne(f0.z); a[3] = (short)bf16_rne(f0.w);
    a[4] = (short)bf16_rne(f1.x); a[5] = (short)bf16_rne(f1.y);
    a[6] = (short)bf16_rne(f1.z); a[7] = (short)bf16_rne(f1.w);
    afrag[kc] = a;
  }

  float dv[4];
#pragma unroll
  for (int r = 0; r < 4; ++r) {
    int row = row0 + lq * 4 + r;
    dv[r] = dinv[row < nrows ? row : 0];
  }

#pragma unroll
  for (int nt = 0; nt < 8; ++nt) {
    f32x4 acc = {0.f, 0.f, 0.f, 0.f};
    const unsigned short* Wb = Wt + (size_t)(nt * 16 + lm) * HD + lq * 8;
#pragma unroll
    for (int kc = 0; kc < 4; ++kc) {
      short8 bfrag = *(const short8*)(Wb + kc * 32);
      acc = __builtin_amdgcn_mfma_f32_16x16x32_bf16(afrag[kc], bfrag, acc, 0, 0, 0);
    }
#pragma unroll
    for (int r = 0; r < 4; ++r) {
      int row = row0 + lq * 4 + r;
      if (row < nrows)
        hs[(size_t)row * HD + nt * 16 + lm] = bf16_rne(acc[r] * dv[r]);
    }
  }
}

// ---------------- row-gather: 16 lanes per node, full 256B row per edge ----------------
// Full-line gathers: 1 edge = 2 fully-used 128B lines; col read once.
// FETCH ~201MB == 8 XCD x 25.6MB hs: each XCD L2 fills each line once (structural floor).
// Stratified sorted-position map (p = gi*8 + s): waves keep ~uniform degree.
__global__ __launch_bounds__(256) void k_gatherR(const uint4* __restrict__ hsv,
                                                 const float* __restrict__ dinv,
                                                 const int2* __restrict__ rows,
                                                 const int* __restrict__ col,
                                                 const int* __restrict__ sortOrd,
                                                 const float* __restrict__ b1,
                                                 const float* __restrict__ uv,
                                                 float2* __restrict__ q) {
  const int s = blockIdx.x & 7;        // position slice
  const int g = blockIdx.x >> 3;       // bucket
  const int t = threadIdx.x;
  const int gi = t >> 4;               // group 0..15 (one node each)
  const int fl = t & 15;               // lane in group: feats [fl*8, fl*8+8)
  const int p = gi * 8 + s;            // stratified sorted position
  const int tloc = sortOrd[g * NPB + p];
  const int node = g * NPB + tloc;
  const bool valid = node < NN;

  int2 be = valid ? rows[node] : make_int2(0, 0);

  float ax[8] = {0.f, 0.f, 0.f, 0.f, 0.f, 0.f, 0.f, 0.f};
  if (valid) acc_row8(ax, hsv[(size_t)node * 16 + fl]);  // self term

  int e = be.x;
  const int eend = be.y;
  for (; e + 3 < eend; e += 4) {
    int c0 = col[e], c1 = col[e + 1], c2 = col[e + 2], c3 = col[e + 3];
    uint4 u0 = hsv[(size_t)c0 * 16 + fl];
    uint4 u1 = hsv[(size_t)c1 * 16 + fl];
    uint4 u2 = hsv[(size_t)c2 * 16 + fl];
    uint4 u3 = hsv[(size_t)c3 * 16 + fl];
    acc_row8(ax, u0); acc_row8(ax, u1); acc_row8(ax, u2); acc_row8(ax, u3);
  }
  for (; e < eend; ++e) acc_row8(ax, hsv[(size_t)col[e] * 16 + fl]);

  // epilogue: relu + projection over own 8 feats, reduce across the 16-lane group
  float di = valid ? dinv[node] : 0.f;
  float s1 = 0.f, s2 = 0.f;
#pragma unroll
  for (int j = 0; j < 8; ++j) {
    int f = fl * 8 + j;
    float h = fmaxf(di * ax[j] + b1[f], 0.f);
    s1 += h * uv[f];
    s2 += h * uv[128 + f];
  }
#pragma unroll
  for (int o = 1; o < 16; o <<= 1) {
    s1 += __shfl_xor(s1, o);
    s2 += __shfl_xor(s2, o);
  }
  if (fl == 0 && valid) q[node] = make_float2(di * s1, di * s2);
}

// ---------------- qagg: conv2+score collapsed (q table 800KB, L2-resident) ----------------
#define LOADQ(P0, P1, P2, P3, pos)                                     \
  {                                                                    \
    P0 = q[col[(pos)]]; P1 = q[col[(pos) + 1]];                        \
    P2 = q[col[(pos) + 2]]; P3 = q[col[(pos) + 3]];                    \
  }
__global__ __launch_bounds__(256) void k_qagg(const float2* __restrict__ q,
                                              const float* __restrict__ dinv,
                                              const int2* __restrict__ rows,
                                              const int* __restrict__ col,
                                              const float* __restrict__ uv,
                                              float2* __restrict__ sv, int n) {
  int i = blockIdx.x * 256 + threadIdx.x;
  if (i >= n) return;
  int2 be = rows[i];
  float2 a = q[i];
  float a1 = a.x, a2 = a.y;
  int e = be.x;
  const int eend = be.y;
  int n4 = (eend - e) >> 2;
  int ep = e;
  e += n4 << 2;
  if (n4) {
    float2 A0, A1, A2, A3, B0, B1, B2, B3;
    LOADQ(A0, A1, A2, A3, ep); ep += 4; n4--;
    while (n4 >= 2) {
      LOADQ(B0, B1, B2, B3, ep); ep += 4;
      a1 += (A0.x + A1.x) + (A2.x + A3.x);
      a2 += (A0.y + A1.y) + (A2.y + A3.y);
      LOADQ(A0, A1, A2, A3, ep); ep += 4;
      a1 += (B0.x + B1.x) + (B2.x + B3.x);
      a2 += (B0.y + B1.y) + (B2.y + B3.y);
      n4 -= 2;
    }
    if (n4) {
      LOADQ(B0, B1, B2, B3, ep);
      a1 += (A0.x + A1.x) + (A2.x + A3.x);
      a2 += (A0.y + A1.y) + (A2.y + A3.y);
      a1 += (B0.x + B1.x) + (B2.x + B3.x);
      a2 += (B0.y + B1.y) + (B2.y + B3.y);
    } else {
      a1 += (A0.x + A1.x) + (A2.x + A3.x);
      a2 += (A0.y + A1.y) + (A2.y + A3.y);
    }
  }
  for (; e < eend; ++e) {
    float2 qq = q[col[e]];
    a1 += qq.x; a2 += qq.y;
  }
  float di = dinv[i];
  sv[i] = make_float2(a1 * di + uv[256], a2 * di + uv[257]);
}

// ---------------- pair outputs ----------------
__global__ void k_pairs(const float2* __restrict__ s, const int* __restrict__ I,
                        const int* __restrict__ J, const float* __restrict__ blin,
                        float* __restrict__ out, int np) {
  int p = blockIdx.x * 256 + threadIdx.x;
  if (p < np) {
    float v = s[I[p]].x + s[J[p]].y + blin[0];
    out[p] = 1.f / (1.f + __expf(-v));
  }
}

extern "C" void kernel_launch(void* const* d_in, const int* in_sizes, int n_in,
                              void* d_out, int out_size, void* d_ws, size_t ws_size,
                              hipStream_t stream) {
  const float* x     = (const float*)d_in[0];
  const int*   eidx  = (const int*)d_in[1];
  const int*   Iidx  = (const int*)d_in[2];
  const int*   Jidx  = (const int*)d_in[3];
  const float* W1    = (const float*)d_in[4];
  const float* b1    = (const float*)d_in[5];
  const float* W2    = (const float*)d_in[6];
  const float* b2    = (const float*)d_in[7];
  const float* Wlin  = (const float*)d_in[8];
  const float* blin  = (const float*)d_in[9];
  const int* src = eidx;
  const int* dst = eidx + NE;

  // workspace layout: hs FIRST so rows are 256B-aligned (row = exactly two 128B lines)
  unsigned short* hs = (unsigned short*)d_ws;         // NN*HD bf16 = 25.6 MB
  float* dinv  = (float*)(hs + (size_t)NN * HD);      // 100000
  float* sv    = dinv + 100000;                       // 200000 (float2/node)
  float* qbuf  = sv + 200000;                         // 200000 (float2/node)
  float* uv    = qbuf + 200000;                       // 264
  unsigned short* wt1 = (unsigned short*)(uv + 264);  // 16384 bf16
  int2* rows   = (int2*)(wt1 + 16384);                // NN int2 (8B-aligned)
  int* col     = (int*)(rows + NN);                   // NB*CAP = 2001920
  int* gcursor = col + NB * CAP;                      // NB (pad 784)
  int* sortOrd = gcursor + 784;                       // NB*NPB = 100096
  unsigned* binned = (unsigned*)(sortOrd + NB * NPB); // NB*CAP x 4B

  float* out = (float*)d_out;

  // ---- prep (weight prep + cursor init, fused) ----
  k_prep<<<66, 256, 0, stream>>>(W1, wt1, W2, Wlin, b2, uv, gcursor);

  // ---- CSR build (fixed-capacity buckets; 4B packed entries) ----
  k_binA<<<NWG, 256, 0, stream>>>(src, dst, gcursor, binned, NE);
  k_binB<<<NB, 256, 0, stream>>>(binned, gcursor, rows, col, dinv, sortOrd);

  // conv1 GEMM -> row-major hs
  k_gemm_mfma<<<(NN + 63) / 64, 256, 0, stream>>>(x, wt1, dinv, hs, NN);

  // conv1 aggregation + relu + score projection (16 lanes/node, full-line gathers)
  k_gatherR<<<NB * 8, 256, 0, stream>>>((const uint4*)hs, dinv, rows, col,
                                        sortOrd, b1, uv, (float2*)qbuf);

  // conv2 + score head collapsed (pipelined gathers)
  k_qagg<<<(NN + 255) / 256, 256, 0, stream>>>((const float2*)qbuf, dinv, rows, col, uv,
                                               (float2*)sv, NN);

  // pair outputs
  k_pairs<<<(NP + 255) / 256, 256, 0, stream>>>((const float2*)sv, Iidx, Jidx, blin, out, NP);
}

// Round 5
// 262.471 us; speedup vs baseline: 1.6196x; 1.0019x over previous
//
#include <hip/hip_runtime.h>
#include <hip/hip_bf16.h>
#include <math.h>

#define NN 100000
#define NE 1600000
#define NP 500000
#define HD 128
#define NPB 128                    // nodes per bucket (pow2)
#define NB 782                     // ceil(NN/NPB)
#define CAP 2560                   // bucket capacity (mean 2048, +11 sigma)
#define CHUNK 4096                 // edges per binning workgroup
#define NWG 391                    // ceil(NE/CHUNK)

typedef __attribute__((ext_vector_type(8))) short short8;   // 8 bf16 = 4 VGPRs
typedef __attribute__((ext_vector_type(4))) float f32x4;

// ---- bf16 helpers ----
__device__ __forceinline__ float bf_lo(unsigned int u) { return __uint_as_float(u << 16); }
__device__ __forceinline__ float bf_hi(unsigned int u) { return __uint_as_float(u & 0xffff0000u); }
__device__ __forceinline__ unsigned short bf16_rne(float f) {
  unsigned int u = __float_as_uint(f);
  u = (u + 0x7fffu + ((u >> 16) & 1u)) >> 16;
  return (unsigned short)u;
}
// accumulate 8 bf16 (one uint4) into ax[8]
__device__ __forceinline__ void acc_row8(float* ax, uint4 u) {
  ax[0] += bf_lo(u.x); ax[1] += bf_hi(u.x);
  ax[2] += bf_lo(u.y); ax[3] += bf_hi(u.y);
  ax[4] += bf_lo(u.z); ax[5] += bf_hi(u.z);
  ax[6] += bf_lo(u.w); ax[7] += bf_hi(u.w);
}

// ---------------- prep (fused): W1 transpose/cast + u-vectors + gcursor init ----------------
__global__ __launch_bounds__(256) void k_prep(const float* __restrict__ W1,
                                              unsigned short* __restrict__ Wt,
                                              const float* __restrict__ W2,
                                              const float* __restrict__ Wl,
                                              const float* __restrict__ b2,
                                              float* __restrict__ uv,
                                              int* __restrict__ gcursor) {
  const int blk = blockIdx.x;
  const int t = threadIdx.x;
  if (blk < 64) {
    int i = blk * 256 + t;           // 16384
    int n = i >> 7, k = i & 127;
    Wt[i] = bf16_rne(W1[k * HD + n]);
  } else if (blk == 64) {
    // u-vectors: u1 = W2@Wl[:128], u2 = W2@Wl[128:], c1/c2 = b2.Wl
    __shared__ float sh[256];
    const int half = t >> 7;
    const int k = t & 127;
    const float* wl = Wl + half * 128;
    float s = 0.f;
    for (int c = 0; c < 128; ++c) s += W2[k * HD + c] * wl[c];
    uv[half * 128 + k] = s;

    sh[t] = b2[k] * Wl[half * 128 + k];
    __syncthreads();
    for (int o = 64; o > 0; o >>= 1) {
      if ((t & 127) < o) sh[t] += sh[t + o];
      __syncthreads();
    }
    if (t == 0) uv[256] = sh[0];
    if (t == 128) uv[257] = sh[128];
  } else {
    for (int i = t; i < NB; i += 256) gcursor[i] = i * CAP;
  }
}

// ---- binA: bin edges into fixed-capacity bucket regions; 4B entry = src | (d&127)<<17 ----
// Rank captured from the pass-1 atomicAdd return (no second LDS-atomic pass).
__global__ __launch_bounds__(256) void k_binA(const int* __restrict__ src,
                                              const int* __restrict__ dst,
                                              int* __restrict__ gcursor,
                                              unsigned* __restrict__ binned, int ne) {
  __shared__ int hist[NB];
  __shared__ int base[NB];
  const int t = threadIdx.x;
  const int e0 = blockIdx.x * CHUNK;

  for (int i = t; i < NB; i += 256) hist[i] = 0;
  __syncthreads();

  int dstv[CHUNK / 256];
  int rank[CHUNK / 256];
#pragma unroll
  for (int k = 0; k < CHUNK / 256; ++k) {
    int e = e0 + k * 256 + t;
    dstv[k] = (e < ne) ? dst[e] : -1;
    rank[k] = (dstv[k] >= 0) ? atomicAdd(&hist[dstv[k] >> 7], 1) : 0;
  }
  __syncthreads();

  for (int i = t; i < NB; i += 256) {
    int c = hist[i];
    base[i] = c ? atomicAdd(&gcursor[i], c) : 0;
  }
  __syncthreads();

#pragma unroll
  for (int k = 0; k < CHUNK / 256; ++k) {
    int d = dstv[k];
    if (d >= 0) {
      int e = e0 + k * 256 + t;
      int pos = base[d >> 7] + rank[k];
      binned[pos] = (unsigned)src[e] | ((unsigned)(d & 127) << 17);
    }
  }
}

// ---- binB: per-node count -> rows + dinv + degree-sorted order, then CSR placement ----
// Entries + per-entry ranks staged in LDS during the count pass; placement is atomic-free.
__global__ __launch_bounds__(256) void k_binB(const unsigned* __restrict__ binned,
                                              const int* __restrict__ gcursor,
                                              int2* __restrict__ rows,
                                              int* __restrict__ col,
                                              float* __restrict__ dinv,
                                              int* __restrict__ sortOrd) {
  __shared__ unsigned lbin[CAP];
  __shared__ unsigned short lrank[CAP];
  __shared__ int hcnt[NPB];
  __shared__ int sc[NPB];
  __shared__ int lcur[NPB];
  __shared__ int h64[64];
  __shared__ int s64[64];
  const int b = blockIdx.x;
  const int t = threadIdx.x;
  const int node0 = b * NPB;
  const int node1 = (node0 + NPB > NN) ? NN : node0 + NPB;
  const int nnode = node1 - node0;
  if (t < NPB) hcnt[t] = 0;
  if (t < 64) h64[t] = 0;
  __syncthreads();

  const int gbase = b * CAP;
  const int gend = gcursor[b];   // after binA: b*CAP + bucket count
  const int cnt = gend - gbase;
  for (int i = gbase + t; i < gend; i += 256) {
    unsigned en = binned[i];
    lbin[i - gbase] = en;
    lrank[i - gbase] = (unsigned short)atomicAdd(&hcnt[en >> 17], 1);
  }
  __syncthreads();

  int v = (t < NPB) ? hcnt[t] : 0;
  if (t < NPB) sc[t] = v;
  __syncthreads();
#pragma unroll
  for (int o = 1; o < NPB; o <<= 1) {
    int add = (t < NPB && t >= o) ? sc[t - o] : 0;
    __syncthreads();
    if (t < NPB) sc[t] += add;
    __syncthreads();
  }
  if (t < NPB) {
    int rp = gbase + sc[t] - v;   // exclusive prefix within bucket
    lcur[t] = rp;                 // placement base (atomic-free)
    if (t < nnode) {
      rows[node0 + t] = make_int2(rp, rp + v);
      dinv[node0 + t] = rsqrtf((float)v + 1.0f);
    }
  }

  // ---- counting sort of the 128 local nodes by degree (invalid t -> deg 0) ----
  const int deg = (t < nnode) ? v : 0;
  const int dcl = deg > 63 ? 63 : deg;
  if (t < NPB) atomicAdd(&h64[dcl], 1);
  __syncthreads();
  int hv = (t < 64) ? h64[t] : 0;
  if (t < 64) s64[t] = hv;
  __syncthreads();
#pragma unroll
  for (int o = 1; o < 64; o <<= 1) {
    int add = (t < 64 && t >= o) ? s64[t - o] : 0;
    __syncthreads();
    if (t < 64) s64[t] += add;
    __syncthreads();
  }
  if (t < 64) h64[t] = s64[t] - hv;  // exclusive base -> cursor
  __syncthreads();
  if (t < NPB) {
    int p = atomicAdd(&h64[dcl], 1);
    sortOrd[b * NPB + p] = t;
  }
  __syncthreads();

  for (int i = t; i < cnt; i += 256) {
    unsigned en = lbin[i];
    col[lcur[en >> 17] + (int)lrank[i]] = (int)(en & 0x1FFFF);
  }
}

// ---------------- MFMA GEMM -> half-row layout ----------------
// hs split into two half-row arrays of 64 bf16 (=128B, one L2 line):
//   half h, row r, local feat c: hs[((h*NN)+r)*64 + c], global feat = h*64+c
__global__ __launch_bounds__(256) void k_gemm_mfma(const float* __restrict__ X,
                                                   const unsigned short* __restrict__ Wt,
                                                   const float* __restrict__ dinv,
                                                   unsigned short* __restrict__ hs,
                                                   int nrows) {
  const int wave = threadIdx.x >> 6;
  const int lane = threadIdx.x & 63;
  const int row0 = blockIdx.x * 64 + wave * 16;
  if (row0 >= nrows) return;
  const int lm = lane & 15;   // A-row / C-col
  const int lq = lane >> 4;   // quad

  int arow = row0 + lm;
  int arowc = arow < nrows ? arow : nrows - 1;  // clamp (stores are guarded)

  short8 afrag[4];
#pragma unroll
  for (int kc = 0; kc < 4; ++kc) {
    int k0 = kc * 32 + lq * 8;
    const float4* p = (const float4*)(X + (size_t)arowc * HD + k0);
    float4 f0 = p[0], f1 = p[1];
    short8 a;
    a[0] = (short)bf16_rne(f0.x); a[1] = (short)bf16_rne(f0.y);
    a[2] = (short)bf16_rne(f0.z); a[3] = (short)bf16_rne(f0.w);
    a[4] = (short)bf16_rne(f1.x); a[5] = (short)bf16_rne(f1.y);
    a[6] = (short)bf16_rne(f1.z); a[7] = (short)bf16_rne(f1.w);
    afrag[kc] = a;
  }

  float dv[4];
#pragma unroll
  for (int r = 0; r < 4; ++r) {
    int row = row0 + lq * 4 + r;
    dv[r] = dinv[row < nrows ? row : 0];
  }

#pragma unroll
  for (int nt = 0; nt < 8; ++nt) {
    f32x4 acc = {0.f, 0.f, 0.f, 0.f};
    const unsigned short* Wb = Wt + (size_t)(nt * 16 + lm) * HD + lq * 8;
#pragma unroll
    for (int kc = 0; kc < 4; ++kc) {
      short8 bfrag = *(const short8*)(Wb + kc * 32);
      acc = __builtin_amdgcn_mfma_f32_16x16x32_bf16(afrag[kc], bfrag, acc, 0, 0, 0);
    }
    const int half = nt >> 2;
    const int loc = (nt & 3) * 16 + lm;
#pragma unroll
    for (int r = 0; r < 4; ++r) {
      int row = row0 + lq * 4 + r;
      if (row < nrows)
        hs[((size_t)half * NN + row) * 64 + loc] = bf16_rne(acc[r] * dv[r]);
    }
  }
}

// ---------------- half-row gather: 8 lanes per node, one full 128B line per edge ----------------
// XCD feature-sharding: half = blockIdx&1 -> even/odd XCDs (round-robin dispatch) each
// touch only 12.8MB of hs -> total L2 fills ~102MB instead of 201MB. Per-edge access is
// still exactly one fully-used 128B line. Per-half partial projections go to qpart[2][NN].
// Stratified degree-sorted positions: p = gi*4 + slice keeps waves degree-uniform.
__global__ __launch_bounds__(256) void k_gatherR(const uint4* __restrict__ hsv,
                                                 const float* __restrict__ dinv,
                                                 const int2* __restrict__ rows,
                                                 const int* __restrict__ col,
                                                 const int* __restrict__ sortOrd,
                                                 const float* __restrict__ b1,
                                                 const float* __restrict__ uv,
                                                 float2* __restrict__ qpart) {
  const int half = blockIdx.x & 1;     // feature half (XCD parity)
  const int slice = (blockIdx.x >> 1) & 3;  // position slice
  const int g = blockIdx.x >> 3;       // bucket
  const int t = threadIdx.x;
  const int gi = t >> 3;               // group 0..31 (one node each)
  const int fl = t & 7;                // lane in group: local feats [fl*8, fl*8+8)
  const int p = gi * 4 + slice;        // stratified sorted position
  const int tloc = sortOrd[g * NPB + p];
  const int node = g * NPB + tloc;
  const bool valid = node < NN;

  int2 be = valid ? rows[node] : make_int2(0, 0);
  const uint4* plane = hsv + (size_t)half * NN * 8;

  float ax[8] = {0.f, 0.f, 0.f, 0.f, 0.f, 0.f, 0.f, 0.f};
  if (valid) acc_row8(ax, plane[(size_t)node * 8 + fl]);  // self term

  int e = be.x;
  const int eend = be.y;
  for (; e + 3 < eend; e += 4) {
    int c0 = col[e], c1 = col[e + 1], c2 = col[e + 2], c3 = col[e + 3];
    uint4 u0 = plane[(size_t)c0 * 8 + fl];
    uint4 u1 = plane[(size_t)c1 * 8 + fl];
    uint4 u2 = plane[(size_t)c2 * 8 + fl];
    uint4 u3 = plane[(size_t)c3 * 8 + fl];
    acc_row8(ax, u0); acc_row8(ax, u1); acc_row8(ax, u2); acc_row8(ax, u3);
  }
  for (; e < eend; ++e) acc_row8(ax, plane[(size_t)col[e] * 8 + fl]);

  // epilogue: relu + projection over own 8 feats, reduce across the 8-lane group
  float di = valid ? dinv[node] : 0.f;
  float s1 = 0.f, s2 = 0.f;
#pragma unroll
  for (int j = 0; j < 8; ++j) {
    int f = half * 64 + fl * 8 + j;
    float h = fmaxf(di * ax[j] + b1[f], 0.f);
    s1 += h * uv[f];
    s2 += h * uv[128 + f];
  }
#pragma unroll
  for (int o = 1; o < 8; o <<= 1) {
    s1 += __shfl_xor(s1, o);
    s2 += __shfl_xor(s2, o);
  }
  if (fl == 0 && valid) qpart[(size_t)half * NN + node] = make_float2(di * s1, di * s2);
}

// ---------------- qred: q[n] = qpart[0][n] + qpart[1][n] ----------------
__global__ void k_qred(const float2* __restrict__ qpart, float2* __restrict__ q, int n) {
  int i = blockIdx.x * 256 + threadIdx.x;
  if (i < n) {
    float2 a = qpart[i];
    float2 b = qpart[(size_t)NN + i];
    q[i] = make_float2(a.x + b.x, a.y + b.y);
  }
}

// ---------------- qagg: conv2+score collapsed (q table 800KB, L2-resident) ----------------
// Degree-sorted thread->node mapping (sortOrd) for wave-uniform inner-loop lengths.
#define LOADQ(P0, P1, P2, P3, pos)                                     \
  {                                                                    \
    P0 = q[col[(pos)]]; P1 = q[col[(pos) + 1]];                        \
    P2 = q[col[(pos) + 2]]; P3 = q[col[(pos) + 3]];                    \
  }
__global__ __launch_bounds__(256) void k_qagg(const float2* __restrict__ q,
                                              const float* __restrict__ dinv,
                                              const int2* __restrict__ rows,
                                              const int* __restrict__ col,
                                              const int* __restrict__ sortOrd,
                                              const float* __restrict__ uv,
                                              float2* __restrict__ sv) {
  const int idx = blockIdx.x * 256 + threadIdx.x;   // grid covers NB*NPB = 100096
  const int g = idx >> 7;
  const int p = idx & 127;
  const int node = g * NPB + sortOrd[idx];
  if (node >= NN) return;
  (void)p;
  int2 be = rows[node];
  float2 a = q[node];
  float a1 = a.x, a2 = a.y;
  int e = be.x;
  const int eend = be.y;
  int n4 = (eend - e) >> 2;
  int ep = e;
  e += n4 << 2;
  if (n4) {
    float2 A0, A1, A2, A3, B0, B1, B2, B3;
    LOADQ(A0, A1, A2, A3, ep); ep += 4; n4--;
    while (n4 >= 2) {
      LOADQ(B0, B1, B2, B3, ep); ep += 4;
      a1 += (A0.x + A1.x) + (A2.x + A3.x);
      a2 += (A0.y + A1.y) + (A2.y + A3.y);
      LOADQ(A0, A1, A2, A3, ep); ep += 4;
      a1 += (B0.x + B1.x) + (B2.x + B3.x);
      a2 += (B0.y + B1.y) + (B2.y + B3.y);
      n4 -= 2;
    }
    if (n4) {
      LOADQ(B0, B1, B2, B3, ep);
      a1 += (A0.x + A1.x) + (A2.x + A3.x);
      a2 += (A0.y + A1.y) + (A2.y + A3.y);
      a1 += (B0.x + B1.x) + (B2.x + B3.x);
      a2 += (B0.y + B1.y) + (B2.y + B3.y);
    } else {
      a1 += (A0.x + A1.x) + (A2.x + A3.x);
      a2 += (A0.y + A1.y) + (A2.y + A3.y);
    }
  }
  for (; e < eend; ++e) {
    float2 qq = q[col[e]];
    a1 += qq.x; a2 += qq.y;
  }
  float di = dinv[node];
  sv[node] = make_float2(a1 * di + uv[256], a2 * di + uv[257]);
}

// ---------------- pair outputs ----------------
__global__ void k_pairs(const float2* __restrict__ s, const int* __restrict__ I,
                        const int* __restrict__ J, const float* __restrict__ blin,
                        float* __restrict__ out, int np) {
  int p = blockIdx.x * 256 + threadIdx.x;
  if (p < np) {
    float v = s[I[p]].x + s[J[p]].y + blin[0];
    out[p] = 1.f / (1.f + __expf(-v));
  }
}

extern "C" void kernel_launch(void* const* d_in, const int* in_sizes, int n_in,
                              void* d_out, int out_size, void* d_ws, size_t ws_size,
                              hipStream_t stream) {
  const float* x     = (const float*)d_in[0];
  const int*   eidx  = (const int*)d_in[1];
  const int*   Iidx  = (const int*)d_in[2];
  const int*   Jidx  = (const int*)d_in[3];
  const float* W1    = (const float*)d_in[4];
  const float* b1    = (const float*)d_in[5];
  const float* W2    = (const float*)d_in[6];
  const float* b2    = (const float*)d_in[7];
  const float* Wlin  = (const float*)d_in[8];
  const float* blin  = (const float*)d_in[9];
  const int* src = eidx;
  const int* dst = eidx + NE;

  // workspace layout: hs FIRST so half-rows are 128B-aligned (one line each)
  unsigned short* hs = (unsigned short*)d_ws;         // NN*HD bf16 = 25.6 MB (2 halves)
  float* dinv  = (float*)(hs + (size_t)NN * HD);      // 100000
  float* sv    = dinv + 100000;                       // 200000 (float2/node)
  float* qbuf  = sv + 200000;                         // 200000 (float2/node)
  float* qpart = qbuf + 200000;                       // 2*NN float2 = 400000
  float* uv    = qpart + 400000;                      // 264
  unsigned short* wt1 = (unsigned short*)(uv + 264);  // 16384 bf16
  int2* rows   = (int2*)(wt1 + 16384);                // NN int2 (8B-aligned)
  int* col     = (int*)(rows + NN);                   // NB*CAP = 2001920
  int* gcursor = col + NB * CAP;                      // NB (pad 784)
  int* sortOrd = gcursor + 784;                       // NB*NPB = 100096
  unsigned* binned = (unsigned*)(sortOrd + NB * NPB); // NB*CAP x 4B

  float* out = (float*)d_out;

  // ---- prep (weight prep + cursor init, fused) ----
  k_prep<<<66, 256, 0, stream>>>(W1, wt1, W2, Wlin, b2, uv, gcursor);

  // ---- CSR build (fixed-capacity buckets; rank-captured, single-atomic-pass) ----
  k_binA<<<NWG, 256, 0, stream>>>(src, dst, gcursor, binned, NE);
  k_binB<<<NB, 256, 0, stream>>>(binned, gcursor, rows, col, dinv, sortOrd);

  // conv1 GEMM -> half-row hs
  k_gemm_mfma<<<(NN + 63) / 64, 256, 0, stream>>>(x, wt1, dinv, hs, NN);

  // conv1 aggregation + relu + score projection (8 lanes/node, XCD-sharded halves)
  k_gatherR<<<NB * 8, 256, 0, stream>>>((const uint4*)hs, dinv, rows, col,
                                        sortOrd, b1, uv, (float2*)qpart);
  k_qred<<<(NN + 255) / 256, 256, 0, stream>>>((const float2*)qpart, (float2*)qbuf, NN);

  // conv2 + score head collapsed (degree-sorted)
  k_qagg<<<(NB * NPB) / 256, 256, 0, stream>>>((const float2*)qbuf, dinv, rows, col,
                                               sortOrd, uv, (float2*)sv);

  // pair outputs
  k_pairs<<<(NP + 255) / 256, 256, 0, stream>>>((const float2*)sv, Iidx, Jidx, blin, out, NP);
}